// Round 7
// baseline (3819.839 us; speedup 1.0000x reference)
//
#include <hip/hip_runtime.h>

typedef unsigned int u32;
typedef _Float16 f16x2 __attribute__((ext_vector_type(2)));

#define TP 600
#define TQ 60
#define BB 64
#define EMB 344
#define HH 256
#define H2 128
#define GG 512

// ---------- fast math helpers ----------
__device__ __forceinline__ float exp2_fast(float x){
#if __has_builtin(__builtin_amdgcn_exp2f)
    return __builtin_amdgcn_exp2f(x);
#else
    return exp2f(x);
#endif
}
__device__ __forceinline__ float rcp_fast(float x){
#if __has_builtin(__builtin_amdgcn_rcpf)
    return __builtin_amdgcn_rcpf(x);
#else
    return 1.0f / x;
#endif
}
__device__ __forceinline__ float sigm_fast(float x){
    return rcp_fast(1.f + exp2_fast(-1.44269504f * x));
}
__device__ __forceinline__ float tanh_fast(float x){
    return 1.f - 2.f * rcp_fast(1.f + exp2_fast(2.88539008f * x));
}
__device__ __forceinline__ float dot2x(u32 w, u32 h, float acc){
    f16x2 wv = __builtin_bit_cast(f16x2, w);
    f16x2 hv = __builtin_bit_cast(f16x2, h);
    acc = fmaf((float)wv.x, (float)hv.x, acc);
    acc = fmaf((float)wv.y, (float)hv.y, acc);
    return acc;
}
// v_dot2_f32_f16: 2 fp16 MACs, fp32 accumulate, ONE instruction
__device__ __forceinline__ float dot2f(u32 w, u32 h, float acc){
#if __has_builtin(__builtin_amdgcn_fdot2)
    return __builtin_amdgcn_fdot2(__builtin_bit_cast(f16x2, w),
                                  __builtin_bit_cast(f16x2, h), acc, false);
#else
    return dot2x(w, h, acc);
#endif
}
__device__ __forceinline__ u32 pack2(float a, float b){
    f16x2 v; v.x = (_Float16)a; v.y = (_Float16)b;
    return __builtin_bit_cast(u32, v);
}
// wave-wide broadcast of lane l's copy of v (VALU pipe, not LDS pipe)
__device__ __forceinline__ u32 lane_bcast(u32 v, int l){
    return (u32)__builtin_amdgcn_readlane((int)v, l);
}
// LDS-only barrier: does NOT drain vmcnt, so global prefetches/stores stay
// in flight across it (the compiler's __syncthreads emits s_waitcnt vmcnt(0)
// which exposed ~900cy HBM latency every step).
__device__ __forceinline__ void bar_lds(){
    asm volatile("s_waitcnt lgkmcnt(0)\n\ts_barrier" ::: "memory");
}

// ---------- prep: transpose weights (fp32 WT4 layout) + fp16 packing ----------
__global__ void prep_kernel(const float* __restrict__ pre0_Wih, const float* __restrict__ pre0_Whh,
                            const float* __restrict__ pre1_Wih, const float* __restrict__ pre1_Whh,
                            const float* __restrict__ Wq, const float* __restrict__ Wp,
                            const float* __restrict__ Whm,
                            const float* __restrict__ Whhm,
                            float* __restrict__ WT0, float* __restrict__ WT1,
                            float* __restrict__ WTq, float* __restrict__ WTp,
                            float* __restrict__ WTz, const float* __restrict__ Wihm,
                            u32* __restrict__ P0hh, u32* __restrict__ P1hh,
                            u32* __restrict__ PMhh, u32* __restrict__ PMwh)
{
    int g = blockIdx.x * blockDim.x + threadIdx.x;
    int gs = gridDim.x * blockDim.x;
    for (int idx = g; idx < 512*344; idx += gs) {
        int j = idx / 344, k = idx - j*344;
        WT0[((k>>2)*512 + j)*4 + (k&3)] = pre0_Wih[idx];
    }
    for (int idx = g; idx < 512*256; idx += gs) {
        int j = idx >> 8, k = idx & 255;
        WT1[((k>>2)*512 + j)*4 + (k&3)] = pre1_Wih[idx];
    }
    for (int idx = g; idx < 256*256; idx += gs) {
        int j = idx >> 8, k = idx & 255;
        WTq[((k>>2)*256 + j)*4 + (k&3)] = Wq[idx];
        WTp[((k>>2)*256 + j)*4 + (k&3)] = Wp[idx];
    }
    for (int idx = g; idx < 512*256; idx += gs) {
        int j = idx >> 8, k = idx & 255;
        WTz[((k>>2)*512 + j)*4 + (k&3)] = Wihm[j*512 + k];
    }
    for (int idx = g; idx < 64*512; idx += gs) {
        int k2 = idx >> 9, j = idx & 511;
        P0hh[idx] = pack2(pre0_Whh[j*128 + 2*k2], pre0_Whh[j*128 + 2*k2 + 1]);
        P1hh[idx] = pack2(pre1_Whh[j*128 + 2*k2], pre1_Whh[j*128 + 2*k2 + 1]);
        PMhh[idx] = pack2(Whhm[j*128 + 2*k2], Whhm[j*128 + 2*k2 + 1]);
    }
    for (int idx = g; idx < 64*256; idx += gs) {
        int k2 = idx >> 8, j = idx & 255;
        PMwh[idx] = pack2(Whm[j*128 + 2*k2], Whm[j*128 + 2*k2 + 1]);
    }
}

// ---------- batched projection ----------
template<int K, int M>
__global__ __launch_bounds__(M)
void proj_kernel(const float* __restrict__ X0, const float* __restrict__ W0,
                 const float* __restrict__ b0, float* __restrict__ C0, int T0,
                 const float* __restrict__ X1, const float* __restrict__ W1,
                 const float* __restrict__ b1, float* __restrict__ C1)
{
    __shared__ float Xs[K*68];
    int t = blockIdx.x;
    const float* X; const float* W; const float* bias; float* C; int trow;
    if (t < T0) { X = X0; W = W0; bias = b0; C = C0; trow = t; }
    else        { X = X1; W = W1; bias = b1; C = C1; trow = t - T0; }
    int j = threadIdx.x;
    for (int b = 0; b < 64; ++b) {
        for (int k = j; k < K; k += M)
            Xs[k*68 + b] = X[(trow*64 + b)*K + k];
    }
    __syncthreads();
    float acc[64];
    float binit = bias ? bias[j] : 0.f;
    #pragma unroll
    for (int b = 0; b < 64; ++b) acc[b] = binit;
    const float4* W4 = (const float4*)W;
    for (int k4 = 0; k4 < K/4; ++k4) {
        float4 w4 = W4[k4*M + j];
        float wv[4] = {w4.x, w4.y, w4.z, w4.w};
        #pragma unroll
        for (int kk = 0; kk < 4; ++kk) {
            int k = 4*k4 + kk;
            #pragma unroll
            for (int b4 = 0; b4 < 16; ++b4) {
                float4 x4 = *((const float4*)&Xs[k*68 + 4*b4]);
                acc[4*b4+0] = fmaf(wv[kk], x4.x, acc[4*b4+0]);
                acc[4*b4+1] = fmaf(wv[kk], x4.y, acc[4*b4+1]);
                acc[4*b4+2] = fmaf(wv[kk], x4.z, acc[4*b4+2]);
                acc[4*b4+3] = fmaf(wv[kk], x4.w, acc[4*b4+3]);
            }
        }
    }
    for (int b = 0; b < 64; ++b)
        C[(trow*64 + b)*M + j] = acc[b];
}

// ---------- Yq precompute ----------
__global__ __launch_bounds__(512)
void yq_kernel(const float* __restrict__ Hq1, const float* __restrict__ Wihm,
               float* __restrict__ Yq)
{
    __shared__ float Xs[256*68];
    int tq = blockIdx.x;
    int j = threadIdx.x;
    for (int b = 0; b < 64; ++b) {
        for (int k = j; k < 256; k += 512)
            Xs[k*68 + b] = Hq1[(tq*64 + b)*256 + k];
    }
    __syncthreads();
    float acc[64];
    #pragma unroll
    for (int b = 0; b < 64; ++b) acc[b] = 0.f;
    const float4* W4 = (const float4*)(Wihm + j*512 + 256);
    for (int k4 = 0; k4 < 64; ++k4) {
        float4 w4 = W4[k4];
        float wv[4] = {w4.x, w4.y, w4.z, w4.w};
        #pragma unroll
        for (int kk = 0; kk < 4; ++kk) {
            int k = 4*k4 + kk;
            #pragma unroll
            for (int b4 = 0; b4 < 16; ++b4) {
                float4 x4 = *((const float4*)&Xs[k*68 + 4*b4]);
                acc[4*b4+0] = fmaf(wv[kk], x4.x, acc[4*b4+0]);
                acc[4*b4+1] = fmaf(wv[kk], x4.y, acc[4*b4+1]);
                acc[4*b4+2] = fmaf(wv[kk], x4.z, acc[4*b4+2]);
                acc[4*b4+3] = fmaf(wv[kk], x4.w, acc[4*b4+3]);
            }
        }
    }
    for (int b = 0; b < 64; ++b)
        Yq[(tq*64 + b)*512 + j] = acc[b];
}

// ---------- pre-BiLSTM recurrence (h discarded; c masked; h = tanh(c)) ----------
// Rewritten: 128 threads; thread j computes gates i,f,g for row j with all
// 192 weight u32 in registers. One LDS-only barrier per step (h exchange via
// 2-buffer hbuf). Depth-2 x prefetch: loads stay in flight across barriers.
__global__ __launch_bounds__(128)
__attribute__((amdgpu_waves_per_eu(1, 1)))
void rec_pre_kernel(const float* __restrict__ Xp, const float* __restrict__ Xq,
                    const u32* __restrict__ Whh,
                    const float* __restrict__ mask_p, const float* __restrict__ mask_q,
                    float* __restrict__ Hp, float* __restrict__ Hq)
{
    int bid = blockIdx.x;
    int sub = bid & 127; int b = sub >> 1; int dir = sub & 1;
    const float* X; const float* mask; float* Hout; int T;
    if (bid < 128) { X = Xp; mask = mask_p; Hout = Hp; T = TP; }
    else           { X = Xq; mask = mask_q; Hout = Hq; T = TQ; }
    int j = threadIdx.x;          // 0..127 : hidden row
    int l = j & 63;
    __shared__ __align__(8) _Float16 hbuf[2][128];
    u32 wi[64], wf[64], wg[64];
    #pragma unroll
    for (int q = 0; q < 64; ++q) {
        wi[q] = Whh[q*512 +       j];
        wf[q] = Whh[q*512 + 128 + j];
        wg[q] = Whh[q*512 + 256 + j];
    }
    hbuf[0][j] = (_Float16)0.f;
    float c = 0.f;
    int t0 = dir ? (T-1) : 0;
    int t1i = (T > 1) ? (dir ? (T-2) : 1) : t0;
    float xi0 = X[(t0*64+b)*512 + j],       xf0 = X[(t0*64+b)*512 + 128 + j],
          xg0 = X[(t0*64+b)*512 + 256 + j], m0  = mask[t0*64+b];
    float xi1 = X[(t1i*64+b)*512 + j],       xf1 = X[(t1i*64+b)*512 + 128 + j],
          xg1 = X[(t1i*64+b)*512 + 256 + j], m1  = mask[t1i*64+b];
    bar_lds();
    int buf = 0;
    const u32* hb32 = (const u32*)hbuf;
    for (int s = 0; s < T; ++s) {
        int ti = dir ? (T-1-s) : s;
        int s2 = (s+2 < T) ? (s+2) : (T-1);
        int t2 = dir ? (T-1-s2) : s2;
        // prefetch step s+2 (2 steps of cover; lgkm barriers don't drain vmcnt)
        float xi2 = X[(t2*64+b)*512 + j],       xf2 = X[(t2*64+b)*512 + 128 + j],
              xg2 = X[(t2*64+b)*512 + 256 + j], m2  = mask[t2*64+b];
        u32 hp = hb32[buf*64 + l];
        float ai0 = xi0, ai1 = 0.f, af0 = xf0, af1 = 0.f, ag0 = xg0, ag1 = 0.f;
        #pragma unroll
        for (int q = 0; q < 64; q += 2) {
            u32 h0 = lane_bcast(hp, q), h1 = lane_bcast(hp, q+1);
            ai0 = dot2f(wi[q],   h0, ai0); af0 = dot2f(wf[q],   h0, af0); ag0 = dot2f(wg[q],   h0, ag0);
            ai1 = dot2f(wi[q+1], h1, ai1); af1 = dot2f(wf[q+1], h1, af1); ag1 = dot2f(wg[q+1], h1, ag1);
        }
        float gi = sigm_fast(ai0 + ai1);
        float gf = sigm_fast(af0 + af1);
        float gg = tanh_fast(ag0 + ag1);
        c = gf*c + gi*gg;
        c *= m0;
        float h = tanh_fast(c);
        hbuf[buf^1][j] = (_Float16)h;
        Hout[(ti*64 + b)*256 + dir*128 + j] = h;
        bar_lds();
        buf ^= 1;
        xi0=xi1; xf0=xf1; xg0=xg1; m0=m1;
        xi1=xi2; xf1=xf2; xg1=xg2; m1=m2;
    }
}

// ---------- Match-LSTM recurrence: one block per (b, dir) ----------
// 3 LDS-only barriers/step. Cell computed redundantly by ALL threads for
// their lane's h-pair -> hp lives in a register (no h16 LDS, no 4th barrier).
// Prefetches/out-store issued post-bar1; vmcnt waits land before use ~a full
// step later (no barrier drains them).
__global__ __launch_bounds__(512)
__attribute__((amdgpu_waves_per_eu(2, 2)))
void match_kernel(const float* __restrict__ ap,   // [600][64][256]
                  const float* __restrict__ aqg,  // [60][64][256]
                  const float* __restrict__ Zp,   // [600][64][512]
                  const float* __restrict__ Yq,   // [60][64][512]
                  const float* __restrict__ Wa,   // [256]
                  const float* __restrict__ mask_p,
                  const u32* __restrict__ PMwh,   // [64][256] packed Wh
                  const u32* __restrict__ PMhh,   // [64][512] packed Whh
                  float* __restrict__ out)        // [600][64][256]
{
    int bid = blockIdx.x; int b = bid >> 1; int dir = bid & 1;
    int tid = threadIdx.x;
    __shared__ __align__(16) u32 sumt16[160];        // [sb][20]: pairs [16sb..16sb+16)
    __shared__ __align__(16) float gates[512];       // nonlinearity pre-applied
    __shared__ __align__(16) _Float16 e16[64];

    int tq = tid >> 3, sb = tid & 7, l = tid & 63;

    // ---- step-invariant register staging ----
    u32 aqr[16];                                     // aq[tq][32sb..32sb+32) fp16 pairs
    if (tq < 60) {
        #pragma unroll
        for (int i = 0; i < 16; ++i) {
            float2 a = *(const float2*)&aqg[(tq*64 + b)*256 + 32*sb + 2*i];
            aqr[i] = pack2(a.x, a.y);
        }
    } else {
        #pragma unroll
        for (int i = 0; i < 16; ++i) aqr[i] = 0u;
    }
    u32 wa_reg[16];                                  // wa pairs [16sb..16sb+16)
    #pragma unroll
    for (int i = 0; i < 16; ++i) {
        float2 w2 = *(const float2*)&Wa[32*sb + 2*i];
        wa_reg[i] = pack2(w2.x, w2.y);
    }
    u32 Yqr[32];                                     // Yqr[r] = pack2(Yq[2r][tid], Yq[2r+1][tid])
    #pragma unroll
    for (int r = 0; r < 30; ++r) {
        float y0 = Yq[((2*r  )*64 + b)*512 + tid];
        float y1 = Yq[((2*r+1)*64 + b)*512 + tid];
        Yqr[r] = pack2(y0, y1);
    }
    Yqr[30] = 0u; Yqr[31] = 0u;
    u32 whh[64];
    #pragma unroll
    for (int q = 0; q < 64; ++q) whh[q] = PMhh[q*512 + tid];
    u32 wh[64];
    {
        int jw = tid & 255;
        #pragma unroll
        for (int q = 0; q < 64; ++q) wh[q] = PMwh[q*256 + jw];
    }

    float c0 = 0.f, c1 = 0.f;                        // cell pair for lane l (redundant x8)
    u32 hp = 0u;                                     // h pair for lane l (fp16x2)
    int ti0 = dir ? (TP-1) : 0;
    float zp_c = Zp[(ti0*64 + b)*512 + tid];
    float ap_c = (tid < 256) ? ap[(ti0*64 + b)*256 + tid] : 0.f;
    float m_c  = mask_p[ti0*64 + b];
    int cls = tid >> 7;                               // gate class, wave-uniform
    const u32 ONE2 = 0x3C003C00u;                     // fp16 (1.0, 1.0)
    float h_out0 = 0.f, h_out1 = 0.f; int ti_prev = 0;
    bar_lds();

    const u32* e32 = (const u32*)e16;

    for (int s = 0; s < TP; ++s) {
        int ti = dir ? (TP-1-s) : s;
        int s1 = (s+1 < TP) ? (s+1) : s;
        int tn = dir ? (TP-1-s1) : s1;

        // ---- P1: hwhh (reg) + sumt = ap + h@Wh.T (tid<256); hp from register ----
        float w0 = 0.f, w1 = 0.f, w2a = 0.f, w3a = 0.f;
        if (tid < 256) {
            float s0 = ap_c, s1a = 0.f, s2 = 0.f, s3 = 0.f;
            #pragma unroll
            for (int q = 0; q < 64; q += 4) {
                u32 h0 = lane_bcast(hp, q),   u1 = lane_bcast(hp, q+1);
                u32 h2v = lane_bcast(hp, q+2), h3 = lane_bcast(hp, q+3);
                w0  = dot2f(whh[q],   h0,  w0);  s0  = dot2f(wh[q],   h0,  s0);
                w1  = dot2f(whh[q+1], u1,  w1);  s1a = dot2f(wh[q+1], u1,  s1a);
                w2a = dot2f(whh[q+2], h2v, w2a); s2  = dot2f(wh[q+2], h2v, s2);
                w3a = dot2f(whh[q+3], h3,  w3a); s3  = dot2f(wh[q+3], h3,  s3);
            }
            float st = (s0 + s1a) + (s2 + s3);
            float so = __shfl_xor(st, 1);
            if ((tid & 1) == 0) {
                int p = tid >> 1;
                sumt16[(p >> 4)*20 + (p & 15)] = pack2(st, so);
            }
        } else {
            #pragma unroll
            for (int q = 0; q < 64; q += 4) {
                u32 h0 = lane_bcast(hp, q),   u1 = lane_bcast(hp, q+1);
                u32 h2v = lane_bcast(hp, q+2), h3 = lane_bcast(hp, q+3);
                w0  = dot2f(whh[q],   h0,  w0);
                w1  = dot2f(whh[q+1], u1,  w1);
                w2a = dot2f(whh[q+2], h2v, w2a);
                w3a = dot2f(whh[q+3], h3,  w3a);
            }
        }
        float hwhh = (w0 + w1) + (w2a + w3a);
        bar_lds();                                    // bar1 (sumt ready)

        // deferred out-store + prefetches: in flight across lgkm barriers,
        // waited only at use (next step) -> HBM latency fully covered
        if (s && tid < 64) {
            float2 hv; hv.x = h_out0; hv.y = h_out1;
            *(float2*)&out[(ti_prev*64 + b)*256 + dir*128 + 2*l] = hv;
        }
        float zp_n = Zp[(tn*64 + b)*512 + tid];
        float ap_n = (tid < 256) ? ap[(tn*64 + b)*256 + tid] : 0.f;
        float m_n  = mask_p[tn*64 + b];

        // ---- P2: scores -> e16 ----
        {
            const uint4* sv4 = (const uint4*)&sumt16[sb*20];
            uint4 sv0 = sv4[0], sv1 = sv4[1], sv2 = sv4[2], sv3 = sv4[3];
            u32 sa[16] = {sv0.x,sv0.y,sv0.z,sv0.w, sv1.x,sv1.y,sv1.z,sv1.w,
                          sv2.x,sv2.y,sv2.z,sv2.w, sv3.x,sv3.y,sv3.z,sv3.w};
            float p0 = 0.f, p1 = 0.f, p2 = 0.f, p3 = 0.f;
            #pragma unroll
            for (int i = 0; i < 16; ++i) {
                f16x2 sm = __builtin_bit_cast(f16x2, aqr[i]) +
                           __builtin_bit_cast(f16x2, sa[i]);      // v_pk_add_f16
                f16x2 wv = __builtin_bit_cast(f16x2, wa_reg[i]);
                float t0 = tanh_fast((float)sm.x);
                float t1 = tanh_fast((float)sm.y);
                if (i & 1) { p2 = fmaf((float)wv.x, t0, p2); p3 = fmaf((float)wv.y, t1, p3); }
                else       { p0 = fmaf((float)wv.x, t0, p0); p1 = fmaf((float)wv.y, t1, p1); }
            }
            float part = (p0 + p1) + (p2 + p3);
            part += __shfl_xor(part, 1);
            part += __shfl_xor(part, 2);
            part += __shfl_xor(part, 4);
            float sc = fminf(9.f, fmaxf(-9.f, part));
            float e = exp2_fast(sc * 1.44269504f);
            if (tq >= 60) e = 0.f;
            if (sb == 0) e16[tq] = (_Float16)e;
        }
        bar_lds();                                    // bar2 (e ready)

        // ---- P4: gates = Zp + rn*(sum_tq e*Yq) + hwhh ; nonlinearity fused ----
        {
            u32 ep = e32[l & 31];                     // coop read: lane holds e-pair
            float y0 = 0.f, y1 = 0.f, S0 = 0.f, S1 = 0.f;
            #pragma unroll
            for (int r4 = 0; r4 < 8; ++r4) {
                u32 e0 = lane_bcast(ep, 4*r4+0), e1 = lane_bcast(ep, 4*r4+1);
                u32 e2 = lane_bcast(ep, 4*r4+2), e3 = lane_bcast(ep, 4*r4+3);
                y0 = dot2f(Yqr[4*r4+0], e0, y0); S0 = dot2f(ONE2, e0, S0);
                y1 = dot2f(Yqr[4*r4+1], e1, y1); S1 = dot2f(ONE2, e1, S1);
                y0 = dot2f(Yqr[4*r4+2], e2, y0); S0 = dot2f(ONE2, e2, S0);
                y1 = dot2f(Yqr[4*r4+3], e3, y1); S1 = dot2f(ONE2, e3, S1);
            }
            float rn = rcp_fast(S0 + S1);
            float g = zp_c + rn * (y0 + y1) + hwhh;
            gates[tid] = (cls == 2) ? tanh_fast(g) : sigm_fast(g);
        }
        bar_lds();                                    // bar3 (gates ready)

        // ---- CELL: all threads compute their lane's pair redundantly ----
        {
            float2 gi2 = *(const float2*)&gates[      2*l];
            float2 gf2 = *(const float2*)&gates[128 + 2*l];
            float2 gg2 = *(const float2*)&gates[256 + 2*l];
            float2 go2 = *(const float2*)&gates[384 + 2*l];
            c0 = gf2.x*c0 + gi2.x*gg2.x;
            c1 = gf2.y*c1 + gi2.y*gg2.y;
            float h0 = go2.x * tanh_fast(c0);
            float h1 = go2.y * tanh_fast(c1);
            h0 *= m_c; h1 *= m_c; c0 *= m_c; c1 *= m_c;
            hp = pack2(h0, h1);
            h_out0 = h0; h_out1 = h1; ti_prev = ti;
        }
        // no barrier needed: next writers of LDS are all behind bar1/bar2
        zp_c = zp_n; ap_c = ap_n; m_c = m_n;
    }
    if (tid < 64) {
        float2 hv; hv.x = h_out0; hv.y = h_out1;
        *(float2*)&out[(ti_prev*64 + b)*256 + dir*128 + 2*l] = hv;
    }
}

// ---------- workspace layout (floats) ----------
#define O_BUFX   0UL          // 19,660,800  Xp0 -> Xp1 -> Zp
#define O_BUFXQ  19660800UL   //  1,966,080  Xq0 -> Xq1 -> Yq
#define O_HP0    21626880UL   //  9,830,400  Hp0 -> ap
#define O_HQ0    31457280UL   //    983,040  Hq0 -> aq
#define O_HP1    32440320UL   //  9,830,400
#define O_HQ1    42270720UL   //    983,040
#define O_WT0    43253760UL   //    176,128
#define O_WT1    43429888UL   //    131,072
#define O_WTQ    43560960UL   //     65,536
#define O_WTP    43626496UL   //     65,536
#define O_WTZ    43692032UL   //    131,072
#define O_P0HH   43823104UL   //     32,768 u32
#define O_P1HH   43855872UL
#define O_PMHH   43888640UL
#define O_PMWH   43921408UL   //     16,384 u32

extern "C" void kernel_launch(void* const* d_in, const int* in_sizes, int n_in,
                              void* d_out, int out_size, void* d_ws, size_t ws_size,
                              hipStream_t stream)
{
    const float* passage  = (const float*)d_in[0];
    const float* question = (const float*)d_in[1];
    const float* mask_p   = (const float*)d_in[2];
    const float* mask_q   = (const float*)d_in[3];
    const float* pre0_Wih = (const float*)d_in[4];
    const float* pre0_Whh = (const float*)d_in[5];
    const float* pre0_b   = (const float*)d_in[6];
    const float* pre1_Wih = (const float*)d_in[7];
    const float* pre1_Whh = (const float*)d_in[8];
    const float* pre1_b   = (const float*)d_in[9];
    const float* mq_Wq    = (const float*)d_in[10];
    const float* mq_Wp    = (const float*)d_in[11];
    const float* mq_bp    = (const float*)d_in[12];
    const float* mq_Wh    = (const float*)d_in[13];
    const float* mq_Wa    = (const float*)d_in[14];
    // d_in[15] = mq_ba: softmax-invariant, skipped
    const float* mq_Wih   = (const float*)d_in[16];
    const float* mq_Whh   = (const float*)d_in[17];
    const float* mq_b     = (const float*)d_in[18];

    float* ws = (float*)d_ws;
    float* bufX  = ws + O_BUFX;
    float* bufXq = ws + O_BUFXQ;
    float* Hp0   = ws + O_HP0;
    float* Hq0   = ws + O_HQ0;
    float* Hp1   = ws + O_HP1;
    float* Hq1   = ws + O_HQ1;
    float* WT0   = ws + O_WT0;
    float* WT1   = ws + O_WT1;
    float* WTq   = ws + O_WTQ;
    float* WTp   = ws + O_WTP;
    float* WTz   = ws + O_WTZ;
    u32*   P0hh  = (u32*)(ws + O_P0HH);
    u32*   P1hh  = (u32*)(ws + O_P1HH);
    u32*   PMhh  = (u32*)(ws + O_PMHH);
    u32*   PMwh  = (u32*)(ws + O_PMWH);
    float* ap = Hp0;   // Hp0 dead after proj1
    float* aq = Hq0;
    float* Zp = bufX;  // Xp1 dead after rec1
    float* Yq = bufXq; // Xq1 dead after rec1

    prep_kernel<<<688, 256, 0, stream>>>(pre0_Wih, pre0_Whh, pre1_Wih, pre1_Whh,
                                         mq_Wq, mq_Wp, mq_Wh, mq_Whh,
                                         WT0, WT1, WTq, WTp, WTz, mq_Wih,
                                         P0hh, P1hh, PMhh, PMwh);
    proj_kernel<EMB, 512><<<660, 512, 0, stream>>>(passage, WT0, pre0_b, bufX, TP,
                                                   question, WT0, pre0_b, bufXq);
    rec_pre_kernel<<<256, 128, 0, stream>>>(bufX, bufXq, P0hh, mask_p, mask_q, Hp0, Hq0);
    proj_kernel<256, 512><<<660, 512, 0, stream>>>(Hp0, WT1, pre1_b, bufX, TP,
                                                   Hq0, WT1, pre1_b, bufXq);
    rec_pre_kernel<<<256, 128, 0, stream>>>(bufX, bufXq, P1hh, mask_p, mask_q, Hp1, Hq1);
    proj_kernel<256, 256><<<660, 256, 0, stream>>>(Hp1, WTp, mq_bp, ap, TP,
                                                   Hq1, WTq, nullptr, aq);
    proj_kernel<256, 512><<<600, 512, 0, stream>>>(Hp1, WTz, mq_b, Zp, TP,
                                                   nullptr, nullptr, nullptr, nullptr);
    yq_kernel<<<60, 512, 0, stream>>>(Hq1, mq_Wih, Yq);
    match_kernel<<<128, 512, 0, stream>>>(ap, aq, Zp, Yq, mq_Wa, mask_p,
                                          PMwh, PMhh, (float*)d_out);
}